// Round 14
// baseline (86.543 us; speedup 1.0000x reference)
//
#include <hip/hip_runtime.h>
#include <math.h>

#define TB   256
#define HH   128     // input H=W
#define OHW  64      // output H=W
#define TR   16      // output rows per tile (4 tiles/plane)
#define N0C  68      // n0 row stride; out col c at index c+2
#define NBLK (16 * 256 * 4)
#define CPX  (NBLK / 8)     // blocks per XCD chunk

typedef float f32x2 __attribute__((ext_vector_type(2)));

__device__ __forceinline__ float sigmoidf(float z) {
    return 1.0f / (1.0f + __expf(-z));
}

__device__ __forceinline__ void gl2lds16(const float* g, float* l) {
    __builtin_amdgcn_global_load_lds(
        (const __attribute__((address_space(1))) void*)g,
        (__attribute__((address_space(3))) void*)l, 16, 0, 0);
}
__device__ __forceinline__ void gl2lds4(const float* g, float* l) {
    __builtin_amdgcn_global_load_lds(
        (const __attribute__((address_space(1))) void*)g,
        (__attribute__((address_space(3))) void*)l, 4, 0, 0);
}

// Per-wave staging: wave w stages ONLY the slab rows its own outputs need
// (waves 0/3 get 11 rows incl. the n0-halo rows, waves 1/2 get 9; boundary
// rows duplicated into disjoint LDS regions). vmcnt is per-wave, so an
// in-wave s_waitcnt vmcnt(0) replaces the first __syncthreads: each wave
// flows load->compute independently. One barrier remains (n0 exchange).
__global__ __launch_bounds__(TB, 6) void fused_densenet_kernel(
    const float* __restrict__ x,
    const float* __restrict__ maxgate,
    const float* __restrict__ mb,
    const float* __restrict__ pconvs,
    const float* __restrict__ pbs,
    const float* __restrict__ pgates,
    const float* __restrict__ gbs,
    float* __restrict__ out)
{
    __shared__ float xs[40][HH];          // 11+9+9+11 per-wave rows (20.5 KB)
    __shared__ float n0s[TR + 2][N0C];    // n0 with 1-halo (4.9 KB)

    const int t     = threadIdx.x;
    const int cc    = t & 63;             // output col
    const int wv    = t >> 6;             // wave 0..3; owns output rows 4wv..4wv+3
    const int bid   = blockIdx.x;
    const int l     = (bid & 7) * CPX + (bid >> 3);   // bijective XCD swizzle
    const int tile  = l & 3;
    const int plane = l >> 2;             // b*256 + c
    const int c     = plane & 255;
    const int r0    = tile * TR;

    // ---- weights/biases (block-uniform address -> SGPR-resident) ----
    // ws rows: 0=maxgate 1=p0 2=p1 3=p2 4=p3 5=gate0 6=gate2(leaf1+node)
    float ws[7][9];
#pragma unroll
    for (int i = 0; i < 9; ++i) {
        ws[0][i] = maxgate[c * 9  + i];
        ws[1][i] = pconvs [c * 36 + i * 4 + 0];
        ws[2][i] = pconvs [c * 36 + i * 4 + 1];
        ws[3][i] = pconvs [c * 36 + i * 4 + 2];
        ws[4][i] = pconvs [c * 36 + i * 4 + 3];
        ws[5][i] = pgates [c * 27 + i * 3 + 0];
        ws[6][i] = pgates [c * 27 + i * 3 + 2];
    }
    const float bmax = mb[c];
    const float bp0 = pbs[c * 4 + 0], bp1 = pbs[c * 4 + 1];
    const float bp2 = pbs[c * 4 + 2], bp3 = pbs[c * 4 + 3];
    const float bg0 = gbs[c * 3 + 0];   // leaf0 gate bias
    const float bg1 = gbs[c * 3 + 1];   // leaf1 gate bias
    const float bg2 = gbs[c * 3 + 2];   // node gate bias

    const float* xplane = x + (size_t)plane * (HH * HH);

    // ---- per-wave async staging into this wave's private slab region ----
    const int  wbase = (wv == 0) ? 0 : (11 + 9 * (wv - 1));   // {0,11,20,29}
    const int  ib0   = 2 * r0 + 8 * wv - ((wv == 0) ? 3 : 1); // first input row
    const int  nw    = (wv == 0 || wv == 3) ? 11 : 9;
    float*     base  = &xs[wbase][0];
    {
        const int lo   = ib0 < 0 ? 0 : ib0;
        const int hie  = ib0 + nw - 1;
        const int hi   = hie > HH - 1 ? HH - 1 : hie;
        const int ztop = lo - ib0;               // 3 for tile0/wave0 else 0
        const int zbot = hie - hi;               // 2 for tile3/wave3 else 0
        for (int r = 0; r < ztop; ++r)
            *reinterpret_cast<f32x2*>(&base[r * HH + 2 * cc]) = (f32x2){0.f, 0.f};
        for (int r = 0; r < zbot; ++r)
            *reinterpret_cast<f32x2*>(&base[(nw - 1 - r) * HH + 2 * cc]) = (f32x2){0.f, 0.f};
        const int    nfl  = (hi - lo + 1) * HH;  // multiple of 128
        const float* gsrc = xplane + lo * HH;
        float*       ldst = base + ztop * HH;
        const int nchunk = nfl >> 8;             // 1KB chunks (64 lanes x 16B)
        for (int k = 0; k < nchunk; ++k)
            gl2lds16(gsrc + (k << 8) + cc * 4, ldst + (k << 8));
        if (nfl & 255) {                         // 512B tail
            const int off = nchunk << 8;
            gl2lds4(gsrc + off + cc,      ldst + off);
            gl2lds4(gsrc + off + 64 + cc, ldst + off + 64);
        }
    }
    // n0 side cols (out cols -1 and 64 are outside image -> 0); no load dep
    if (wv == 1 && cc < 2 * (TR + 2)) n0s[cc >> 1][(cc & 1) ? 66 : 1] = 0.f;

    // wait for THIS WAVE's loads only (no block barrier)
    asm volatile("s_waitcnt vmcnt(0)" ::: "memory");

    const int roff = (wv == 0) ? 2 : 0;   // local row of first own window row

    // ---- n0 halo rows, folded into waves 0/3 (3 convs only) ----
    if (wv == 0) {                        // gr = r0-1, local rows 0..2
        float n0v = 0.f;
        if (r0 > 0) {
            float ag = 0.f, q0 = 0.f, q1 = 0.f;
#pragma unroll
            for (int dr = 0; dr < 3; ++dr) {
                const float* row = &base[dr * HH];
                const float v0 = cc ? row[2 * cc - 1] : 0.f;
                const f32x2 d  = *reinterpret_cast<const f32x2*>(&row[2 * cc]);
                ag += v0 * ws[5][3*dr] + d.x * ws[5][3*dr+1] + d.y * ws[5][3*dr+2];
                q0 += v0 * ws[1][3*dr] + d.x * ws[1][3*dr+1] + d.y * ws[1][3*dr+2];
                q1 += v0 * ws[2][3*dr] + d.x * ws[2][3*dr+1] + d.y * ws[2][3*dr+2];
            }
            const float sg = sigmoidf(ag + bg0);
            n0v = sg * (q0 + bp0) + (1.f - sg) * (q1 + bp1);
        }
        n0s[0][cc + 2] = n0v;
    }
    if (wv == 3) {                        // gr = r0+16, local rows 8..10
        float n0v = 0.f;
        if (r0 + TR < OHW) {
            float ag = 0.f, q0 = 0.f, q1 = 0.f;
#pragma unroll
            for (int dr = 0; dr < 3; ++dr) {
                const float* row = &base[(8 + dr) * HH];
                const float v0 = cc ? row[2 * cc - 1] : 0.f;
                const f32x2 d  = *reinterpret_cast<const f32x2*>(&row[2 * cc]);
                ag += v0 * ws[5][3*dr] + d.x * ws[5][3*dr+1] + d.y * ws[5][3*dr+2];
                q0 += v0 * ws[1][3*dr] + d.x * ws[1][3*dr+1] + d.y * ws[1][3*dr+2];
                q1 += v0 * ws[2][3*dr] + d.x * ws[2][3*dr+1] + d.y * ws[2][3*dr+2];
            }
            const float sg = sigmoidf(ag + bg0);
            n0v = sg * (q0 + bp0) + (1.f - sg) * (q1 + bp1);
        }
        n0s[TR + 1][cc + 2] = n0v;
    }

    // ---- stage-1: 4 own rows, 1 col per lane ----
    float o1[4], n1p[4];
#pragma unroll
    for (int k = 0; k < 4; ++k) {
        const int lw = 2 * k + roff;      // local window top row
        const int gr = r0 + 4 * wv + k;
        float a[7];
#pragma unroll
        for (int ci = 0; ci < 7; ++ci) a[ci] = 0.f;
        float mp = -INFINITY;
#pragma unroll
        for (int dr = 0; dr < 3; ++dr) {
            const float* row = &base[(lw + dr) * HH];
            const float v0 = cc ? row[2 * cc - 1] : 0.f;
            const f32x2 d  = *reinterpret_cast<const f32x2*>(&row[2 * cc]);
            const bool rowok = (gr > 0) | (dr > 0);
            const float h = fmaxf(fmaxf(cc ? v0 : -INFINITY, d.x), d.y);
            mp = fmaxf(mp, rowok ? h : -INFINITY);
#pragma unroll
            for (int ci = 0; ci < 7; ++ci)
                a[ci] += v0 * ws[ci][3*dr] + d.x * ws[ci][3*dr+1] + d.y * ws[ci][3*dr+2];
        }
        const float sg0 = sigmoidf(a[5] + bg0);
        n0s[4 * wv + k + 1][cc + 2] = sg0 * (a[1] + bp0) + (1.f - sg0) * (a[2] + bp1);
        const float sg1 = sigmoidf(a[6] + bg1);   // leaf1 gate: bias gbs[:,1]
        n1p[k] = sg1 * (a[3] + bp2) + (1.f - sg1) * (a[4] + bp3);
        o1[k]  = mp * (a[0] + bmax);
    }
    __syncthreads();    // the only block barrier: n0 exchange

    // ---- stage 2: node gate conv on n0 (stride 1, pad 1) + combine + store ----
    float* oplane = out + (size_t)plane * (OHW * OHW);
#pragma unroll
    for (int k = 0; k < 4; ++k) {
        const int lr = 4 * wv + k;
        float ag = 0.f;
#pragma unroll
        for (int dr = 0; dr < 3; ++dr) {
            const float* nr = &n0s[lr + dr][0];
            ag += nr[cc + 1] * ws[6][3*dr] + nr[cc + 2] * ws[6][3*dr+1]
                + nr[cc + 3] * ws[6][3*dr+2];
        }
        const float g   = sigmoidf(ag + bg2);     // node gate: bias gbs[:,2]
        const float n0c = n0s[lr + 1][cc + 2];
        __builtin_nontemporal_store(o1[k] + n0c * g + n1p[k] * (1.f - g),
                                    oplane + (r0 + lr) * OHW + cc);
    }
}

extern "C" void kernel_launch(void* const* d_in, const int* in_sizes, int n_in,
                              void* d_out, int out_size, void* d_ws, size_t ws_size,
                              hipStream_t stream) {
    const float* x       = (const float*)d_in[0];
    const float* maxgate = (const float*)d_in[1];
    const float* mb      = (const float*)d_in[2];
    const float* pconvs  = (const float*)d_in[3];
    const float* pbs     = (const float*)d_in[4];
    const float* pgates  = (const float*)d_in[5];
    const float* gbs     = (const float*)d_in[6];
    float* out           = (float*)d_out;

    fused_densenet_kernel<<<NBLK, TB, 0, stream>>>(
        x, maxgate, mb, pconvs, pbs, pgates, gbs, out);
}